// Round 4
// baseline (96.350 us; speedup 1.0000x reference)
//
#include <hip/hip_runtime.h>
#include <cmath>

namespace {

typedef _Float16 h8 __attribute__((ext_vector_type(8)));

constexpr int C_     = 64;
constexpr int L_     = 32768;
constexpr int TILE   = 8192;
constexpr int HALO   = 776;           // receptive field 765, rounded to unit-8 frontier
constexpr int NB     = TILE + HALO;   // 8968 halfs
constexpr int NU     = NB / 8;        // 1121 h8 units
constexpr int HALO_U = HALO / 8;      // 97
constexpr int NT     = L_ / TILE;     // 4
constexpr int BLK    = 256;
// LDS padded: unit gu lives at half-offset 8*gu + 8*(gu>>2)  (stride 80B per 4 units)
constexpr int LDSH   = 8 * NU + 8 * ((NU + 3) / 4);

__device__ __forceinline__ int uoff(int gu) { return 8 * gu + ((gu >> 2) << 3); }

__device__ __forceinline__ h8 ld8(const _Float16* p) { return *reinterpret_cast<const h8*>(p); }
__device__ __forceinline__ void st8(_Float16* p, h8 v) { *reinterpret_cast<h8*>(p) = v; }
__device__ __forceinline__ float4 ld4f(const float* p) { return *reinterpret_cast<const float4*>(p); }
__device__ __forceinline__ void st4f(float* p, float4 v) { *reinterpret_cast<float4*>(p) = v; }
__device__ __forceinline__ h8 sp8(_Float16 v) { return (h8){v,v,v,v,v,v,v,v}; }

template<int K>
__device__ __forceinline__ h8 shconc(h8 A, h8 B) {
    return __builtin_shufflevector(A, B, K, K+1, K+2, K+3, K+4, K+5, K+6, K+7);
}

// gelu(v) = v * sigmoid(1.59577*v + 0.0713548*v^3); max |diff vs erf-gelu| ~5e-4
__device__ __forceinline__ float gelu_f(float v) {
    const float z = v * (1.5957691216057308f + 0.0713548162726f * v * v);
    const float e = __expf(-z);
    return v * __builtin_amdgcn_rcpf(1.0f + e);
}

// Frontier (valid-start unit) per level: x:0 -> L1:1 -> L2:2 -> L4:4 -> L8:7
// -> L16:13 -> L32:25 -> L64:49 -> L128:97 == HALO_U. Level k computes units
// gu >= STARTU_k; its taps land >= previous level's start (verified recursion),
// so stale/skipped units are never read.
template<int D, int STARTU, bool FIRST, bool LAST>
__device__ __forceinline__ void level(_Float16* __restrict__ buf,
                                      h8* lw, h8* yacc,
                                      const float* h0v, const float* h1v,
                                      float wi, float w0, float w9,
                                      int u0, int myU)
{
    if (u0 + 4 < STARTU) return;   // no active unit on this thread

    _Float16 c1[4], c0[4];
#pragma unroll
    for (int t = 0; t < 4; ++t) {
        c1[t] = (_Float16)(wi * h1v[t]);
        c0[t] = (_Float16)(LAST ? w0 * h0v[t] : h0v[t]);
    }

    if constexpr (D < 8) {
        constexpr int NL = (D == 4) ? 2 : 1;     // left units needed
        h8 X[NL + 5];                            // X[i] = unit u0 - NL + i
#pragma unroll
        for (int i = 0; i < NL; ++i) {
            int g = u0 - NL + i; if (g < 0) g = 0;
            X[i] = ld8(&buf[uoff(g)]);
        }
        if constexpr (FIRST) {
#pragma unroll
            for (int u = 0; u < 5; ++u) {
                int g = u0 + u; if (g > NU - 1) g = NU - 1;
                X[NL + u] = ld8(&buf[uoff(g)]);
            }
        } else {
#pragma unroll
            for (int u = 0; u < 5; ++u) X[NL + u] = lw[u];
        }
#pragma unroll
        for (int u = 0; u < 5; ++u) {
            const int gu = u0 + u;
            const h8 T3 = X[NL + u];
            if constexpr (FIRST) {
                yacc[u] = sp8((_Float16)0.f);
                lw[u]   = T3;
                if ((u < myU) && gu >= HALO_U) yacc[u] = sp8((_Float16)w9) * T3;
            }
            if ((u < myU) && gu >= STARTU) {
                h8 T0, T1, T2;
                if constexpr (D == 1) {          // taps at -3,-2,-1 halfs
                    T0 = shconc<5>(X[NL+u-1], T3);
                    T1 = shconc<6>(X[NL+u-1], T3);
                    T2 = shconc<7>(X[NL+u-1], T3);
                } else if constexpr (D == 2) {   // -6,-4,-2
                    T0 = shconc<2>(X[NL+u-1], T3);
                    T1 = shconc<4>(X[NL+u-1], T3);
                    T2 = shconc<6>(X[NL+u-1], T3);
                } else {                         // D==4: -12,-8,-4
                    T0 = shconc<4>(X[NL+u-2], X[NL+u-1]);
                    T1 = X[NL+u-1];
                    T2 = shconc<4>(X[NL+u-1], T3);
                }
                if (gu >= HALO_U)
                    yacc[u] += sp8(c1[0])*T0 + sp8(c1[1])*T1 + sp8(c1[2])*T2 + sp8(c1[3])*T3;
                const h8 nl = sp8(c0[0])*T0 + sp8(c0[1])*T1 + sp8(c0[2])*T2 + sp8(c0[3])*T3;
                if constexpr (LAST) yacc[u] += nl; else lw[u] = nl;
            }
        }
    } else {
        constexpr int UD = D / 8;                // unit stride of dilation
        h8 T0a[5], T1a[5], T2a[5];
        if constexpr (UD <= 4) {
            // contiguous span [u0-3UD, u0) covers all out-of-thread taps
            h8 R[3 * UD];
#pragma unroll
            for (int i = 0; i < 3 * UD; ++i) {
                int g = u0 - 3 * UD + i; if (g < 0) g = 0;
                R[i] = ld8(&buf[uoff(g)]);
            }
#pragma unroll
            for (int u = 0; u < 5; ++u) {
                const int r0 = u - 3 * UD, r1 = u - 2 * UD, r2 = u - UD;
                T0a[u] = (r0 >= 0) ? lw[r0 < 0 ? 0 : r0] : R[u];
                T1a[u] = (r1 >= 0) ? lw[r1 < 0 ? 0 : r1]
                                   : R[(u + UD) < 3*UD ? (u + UD) : (3*UD - 1)];
                T2a[u] = (r2 >= 0) ? lw[r2 < 0 ? 0 : r2]
                                   : R[(u + 2*UD) < 3*UD ? (u + 2*UD) : (3*UD - 1)];
            }
        } else {
            // D=64,128: three disjoint runs, all taps from LDS
            h8 R[3][5];
#pragma unroll
            for (int m = 0; m < 3; ++m) {
#pragma unroll
                for (int u = 0; u < 5; ++u) {
                    int g = u0 + u - (m + 1) * UD; if (g < 0) g = 0;
                    R[m][u] = ld8(&buf[uoff(g)]);
                }
            }
#pragma unroll
            for (int u = 0; u < 5; ++u) { T0a[u] = R[2][u]; T1a[u] = R[1][u]; T2a[u] = R[0][u]; }
        }
#pragma unroll
        for (int u = 0; u < 5; ++u) {
            const int gu = u0 + u;
            if ((u < myU) && gu >= STARTU) {
                const h8 T3 = lw[u];
                const h8 T0 = T0a[u], T1 = T1a[u], T2 = T2a[u];
                if (gu >= HALO_U)
                    yacc[u] += sp8(c1[0])*T0 + sp8(c1[1])*T1 + sp8(c1[2])*T2 + sp8(c1[3])*T3;
                const h8 nl = sp8(c0[0])*T0 + sp8(c0[1])*T1 + sp8(c0[2])*T2 + sp8(c0[3])*T3;
                if constexpr (LAST) yacc[u] += nl; else lw[u] = nl;
            }
        }
    }
}

template<int STARTU>
__device__ __forceinline__ void publish(_Float16* __restrict__ buf, const h8* lw,
                                        int u0, int myU)
{
    if (u0 + 4 < STARTU) return;
#pragma unroll
    for (int u = 0; u < 5; ++u) {
        const int gu = u0 + u;
        if ((u < myU) && gu >= STARTU) st8(&buf[uoff(gu)], lw[u]);
    }
}

__global__ __launch_bounds__(BLK, 4)
void cmrc_kernel(const float* __restrict__ x,
                 const float* __restrict__ h0,
                 const float* __restrict__ h1,
                 const float* __restrict__ w,
                 float* __restrict__ out)
{
    __shared__ _Float16 buf[LDSH];

    const int tid  = threadIdx.x;
    const int blk  = blockIdx.x;
    const int tile = blk % NT;
    const int bc   = blk / NT;            // b*C + c
    const int c    = bc % C_;
    const long row = (long)bc * L_;
    const int  t0  = tile * TILE - HALO;  // global pos of buffer p=0

    float h0v[4], h1v[4];
#pragma unroll
    for (int k = 0; k < 4; ++k) { h0v[k] = h0[c*4+k]; h1v[k] = h1[c*4+k]; }
    float wv[10];
#pragma unroll
    for (int i = 0; i < 10; ++i) wv[i] = w[c*10+i];

    // Stage x as fp16 (coalesced global reads; zeros left of t=0)
#pragma unroll
    for (int j = 0; j < 5; ++j) {
        const int un = tid + j * BLK;
        if (un < NU) {
            const int p = 8 * un;
            const int t = t0 + p;
            float4 xa = make_float4(0.f,0.f,0.f,0.f);
            float4 xb = make_float4(0.f,0.f,0.f,0.f);
            if (t >= 0)     xa = ld4f(&x[row + t]);
            if (t + 4 >= 0) xb = ld4f(&x[row + t + 4]);
            h8 hv;
            hv[0]=(_Float16)xa.x; hv[1]=(_Float16)xa.y; hv[2]=(_Float16)xa.z; hv[3]=(_Float16)xa.w;
            hv[4]=(_Float16)xb.x; hv[5]=(_Float16)xb.y; hv[6]=(_Float16)xb.z; hv[7]=(_Float16)xb.w;
            st8(&buf[uoff(un)], hv);
        }
    }
    __syncthreads();

    // Contiguous ownership: threads 0..96 own 5 units, 97..255 own 4.
    const int u0  = 4 * tid + (tid < HALO_U ? tid : HALO_U);
    const int myU = (tid < HALO_U) ? 5 : 4;

    h8 lw[5];    // running low residual (own units, registers)
    h8 yacc[5];  // packed y accumulator

    level<1,   1,  true,  false>(buf, lw, yacc, h0v, h1v, wv[8], 0.f, wv[9], u0, myU);
    __syncthreads(); publish<1>(buf, lw, u0, myU);  __syncthreads();
    level<2,   2,  false, false>(buf, lw, yacc, h0v, h1v, wv[7], 0.f, 0.f, u0, myU);
    __syncthreads(); publish<2>(buf, lw, u0, myU);  __syncthreads();
    level<4,   4,  false, false>(buf, lw, yacc, h0v, h1v, wv[6], 0.f, 0.f, u0, myU);
    __syncthreads(); publish<4>(buf, lw, u0, myU);  __syncthreads();
    level<8,   7,  false, false>(buf, lw, yacc, h0v, h1v, wv[5], 0.f, 0.f, u0, myU);
    __syncthreads(); publish<7>(buf, lw, u0, myU);  __syncthreads();
    level<16,  13, false, false>(buf, lw, yacc, h0v, h1v, wv[4], 0.f, 0.f, u0, myU);
    __syncthreads(); publish<13>(buf, lw, u0, myU); __syncthreads();
    level<32,  25, false, false>(buf, lw, yacc, h0v, h1v, wv[3], 0.f, 0.f, u0, myU);
    __syncthreads(); publish<25>(buf, lw, u0, myU); __syncthreads();
    level<64,  49, false, false>(buf, lw, yacc, h0v, h1v, wv[2], 0.f, 0.f, u0, myU);
    __syncthreads(); publish<49>(buf, lw, u0, myU); __syncthreads();
    level<128, 97, false, true >(buf, lw, yacc, h0v, h1v, wv[1], wv[0], 0.f, u0, myU);

    // Epilogue: fp32 GELU (sigmoid form), 2x float4 stores per unit
#pragma unroll
    for (int u = 0; u < 5; ++u) {
        const int gu = u0 + u;
        if ((u < myU) && gu >= HALO_U) {
            const h8 v = yacc[u];
            float4 oa, ob;
            oa.x = gelu_f((float)v[0]); oa.y = gelu_f((float)v[1]);
            oa.z = gelu_f((float)v[2]); oa.w = gelu_f((float)v[3]);
            ob.x = gelu_f((float)v[4]); ob.y = gelu_f((float)v[5]);
            ob.z = gelu_f((float)v[6]); ob.w = gelu_f((float)v[7]);
            const long idx = row + (t0 + 8 * gu);
            st4f(&out[idx], oa);
            st4f(&out[idx + 4], ob);
        }
    }
}

}  // namespace

extern "C" void kernel_launch(void* const* d_in, const int* in_sizes, int n_in,
                              void* d_out, int out_size, void* d_ws, size_t ws_size,
                              hipStream_t stream)
{
    const float* x  = (const float*)d_in[0];
    const float* h0 = (const float*)d_in[1];
    const float* h1 = (const float*)d_in[2];
    const float* w  = (const float*)d_in[3];
    float* out = (float*)d_out;

    const int nblocks = (out_size / L_) * NT;   // B*C*NT = 2048
    cmrc_kernel<<<nblocks, BLK, 0, stream>>>(x, h0, h1, w, out);
}